// Round 17
// baseline (120.627 us; speedup 1.0000x reference)
//
#include <hip/hip_runtime.h>
#include <math.h>

#define NB 4
#define NPI 12000
#define NM 32
#define NPTS (NB*NPI*NM)      // 1536000
#define NPIL (NB*NPI)         // 48000

// k_moments config
#define K1_BLOCKS 1500
#define K1_STRIDE (K1_BLOCKS*256)   // 384000
#define K1_ITERS 4                  // NPTS / K1_STRIDE
#define NMOM 54                     // 9 Sf + 45 Sff

// heavy-kernel config
#define CHUNK 128
#define NBATCH (NPTS/CHUNK)   // 12000
#define SB 768                // 3 blocks/CU resident (LDS 53760 <= 54613)

typedef __attribute__((ext_vector_type(8))) short bfrag;     // 8 bf16 = 4 VGPRs
typedef __attribute__((ext_vector_type(16))) float f32x16;   // MFMA 32x32 acc

// ---------------------------------------------------------------- helpers

__device__ __forceinline__ void make_f(float4 v, int4 cc, int np, int m, float zc, float f[9]) {
  const float cx = ((float)cc.w + 0.5f) * 0.16f + 0.0f;
  const float cy = ((float)cc.z + 0.5f) * 0.16f - 39.68f;
  f[0] = v.x; f[1] = v.y; f[2] = v.z; f[3] = v.w;
  f[4] = v.x - cx; f[5] = v.y - cy; f[6] = cx; f[7] = cy; f[8] = zc;
  const float msk = (m < np) ? 1.0f : 0.0f;
#pragma unroll
  for (int i = 0; i < 9; ++i) f[i] *= msk;
}

// ------------------------------------------------- K1: f-moments

__global__ __launch_bounds__(256) void k_moments(
    const float4* __restrict__ vox, const int4* __restrict__ coords,
    const int* __restrict__ npnts, float* __restrict__ P1) {
  const int t = blockIdx.x * 256 + threadIdx.x;
  float acc[NMOM];
#pragma unroll
  for (int v = 0; v < NMOM; ++v) acc[v] = 0.0f;

#pragma unroll
  for (int j = 0; j < K1_ITERS; ++j) {
    const int pt = t + j * K1_STRIDE;
    const int pil = pt >> 5;
    const int m = pt & 31;
    const float4 v = vox[pt];
    const int4 cc = coords[pil];
    const int np = npnts[pil];
    float z = v.z;
#pragma unroll
    for (int s = 1; s < 32; s <<= 1) z += __shfl_xor(z, s, 32);
    const float zc = z * (1.0f / 32.0f);
    float f[9];
    make_f(v, cc, np, m, zc, f);
    int vi = 0;
#pragma unroll
    for (int i = 0; i < 9; ++i) acc[vi++] += f[i];
#pragma unroll
    for (int i = 0; i < 9; ++i)
#pragma unroll
      for (int jj = i; jj < 9; ++jj) acc[vi++] += f[i] * f[jj];
  }

#pragma unroll
  for (int v = 0; v < NMOM; ++v) {
    float x = acc[v];
#pragma unroll
    for (int s = 1; s < 64; s <<= 1) x += __shfl_xor(x, s, 64);
    acc[v] = x;
  }
  __shared__ float red[4][NMOM];
  const int wave = threadIdx.x >> 6, lane = threadIdx.x & 63;
  if (lane == 0) {
#pragma unroll
    for (int v = 0; v < NMOM; ++v) red[wave][v] = acc[v];
  }
  __syncthreads();
  if (threadIdx.x < NMOM) {
    float s = red[0][threadIdx.x] + red[1][threadIdx.x] + red[2][threadIdx.x] + red[3][threadIdx.x];
    P1[threadIdx.x * K1_BLOCKS + blockIdx.x] = s;
  }
}

// ------------------------------------------------- generic row reduce (f32 -> f64)

__global__ __launch_bounds__(256) void k_rowreduce(
    const float* __restrict__ src, double* __restrict__ dst, int ncols) {
  const int row = blockIdx.x;
  const float* p = src + row * ncols;
  double sd = 0.0;
  for (int i = threadIdx.x; i < ncols; i += 256) sd += (double)p[i];
#pragma unroll
  for (int s = 1; s < 64; s <<= 1) sd += __shfl_xor(sd, s, 64);
  __shared__ double rd[4];
  const int wave = threadIdx.x >> 6, lane = threadIdx.x & 63;
  if (lane == 0) rd[wave] = sd;
  __syncthreads();
  if (threadIdx.x == 0) dst[row] = rd[0] + rd[1] + rd[2] + rd[3];
}

// ------------------------------------------------- finalize layer-1 BN params

__global__ void k_fin1(const double* __restrict__ T1, const float* __restrict__ W1,
                       const float* __restrict__ g1, const float* __restrict__ b1,
                       float* __restrict__ params) {
  const int c = threadIdx.x;  // 64
  double w[9];
#pragma unroll
  for (int i = 0; i < 9; ++i) w[i] = (double)W1[i * 64 + c];
  double mean = 0.0;
#pragma unroll
  for (int i = 0; i < 9; ++i) mean += w[i] * T1[i];
  mean /= (double)NPTS;
  double e2 = 0.0;
  int v = 9;
#pragma unroll
  for (int i = 0; i < 9; ++i)
#pragma unroll
    for (int j = i; j < 9; ++j) {
      const double t = T1[v++] * w[i] * w[j];
      e2 += (i == j) ? t : 2.0 * t;
    }
  e2 /= (double)NPTS;
  const double var = e2 - mean * mean;
  const double a = (double)g1[c] / sqrt(var + 0.001);
  params[c] = (float)a;
  params[64 + c] = (float)((double)b1[c] - mean * a);
}

// ------------------------------------------------- K3: both layers via MFMA, v3
// R16 post-mortem: still DS-bound (6.19M bank-conflicts; f round-trip + 128
// scalar b16 h1-writebacks dominate the LDS pipe). v3 changes:
// (1) f LDS round-trip REMOVED -- the phase-A A-fragment (row=lane&31=point,
//     k=koff+e) is exactly the f this lane computed: pack in registers.
// (2) h1 stored as ONE u32 plane (lo16<<16 | hi16): 32 ds_write_b32 instead
//     of 128 ds_write_b16; read side unpacks with shift/or (v_perm-foldable).
// (3) redS/redQ aliased onto dead W1T staging (barrier-separated) -> LDS
//     53760 B -> 3 blocks/CU (12 waves vs 8). SB 512->768.
// Swizzles: h1p col(u32) ^= (row&7)<<2; W2T col(u16) ^= (row&7)<<3 -- 16B
// granularity preserved, 4-way residual on reads, conflict-free writes.

__global__ __launch_bounds__(256) void k_stats2(
    const float4* __restrict__ vox, const int4* __restrict__ coords,
    const int* __restrict__ npnts, const float* __restrict__ W1,
    const float* __restrict__ W2, const float* __restrict__ g2,
    const float* __restrict__ params, float* __restrict__ P2,
    float* __restrict__ Y2SEL) {
  __shared__ __align__(16) unsigned short W1Thi[64][16];   // 2048 B (redS aliases after loop)
  __shared__ __align__(16) unsigned short W1Tlo[64][16];   // 2048 B (redQ aliases after loop)
  __shared__ __align__(16) float a1s[64], b1s[64];         //  512 B
  __shared__ __align__(16) unsigned int  h1p[128][64];     // 32768 B (swz, lo|hi packed)
  __shared__ __align__(16) unsigned short W2Thi[64][64];   //  8192 B (swz)
  __shared__ __align__(16) unsigned short W2Tlo[64][64];   //  8192 B (swz)
  // total 53760 B <= 54613 -> 3 blocks/CU

  const int t = threadIdx.x;
  if (t < 64) { a1s[t] = params[t]; b1s[t] = params[64 + t]; }
  // stage W1^T split (k padded 9->16): W1T[ch][k]
  for (int i = t; i < 1024; i += 256) {
    const int c = i >> 4, k = i & 15;
    const float x = (k < 9) ? W1[k * 64 + c] : 0.0f;
    const unsigned int b = __float_as_uint(x);
    W1Thi[c][k] = (unsigned short)(b >> 16);
    const float r = x - __uint_as_float(b & 0xFFFF0000u);
    W1Tlo[c][k] = (unsigned short)(__float_as_uint(r) >> 16);
  }
  // stage W2^T split, swizzled: element (ch,k) at col k ^ ((ch&7)<<3)
  for (int i = t; i < 4096; i += 256) {
    const int k = i >> 6, c = i & 63;
    const float x = W2[i];
    const unsigned int b = __float_as_uint(x);
    const float r = x - __uint_as_float(b & 0xFFFF0000u);
    const int kc = k ^ ((c & 7) << 3);
    W2Thi[c][kc] = (unsigned short)(b >> 16);
    W2Tlo[c][kc] = (unsigned short)(__float_as_uint(r) >> 16);
  }

  const int lane = t & 63;
  const int wv = t >> 6;                      // wave owns pillar wv of each batch
  const int ch = lane & 31;                   // tile-local channel / point id
  const float sg0 = (g2[ch] >= 0.0f) ? 1.0f : -1.0f;
  const float sg1 = (g2[32 + ch] >= 0.0f) ? 1.0f : -1.0f;
  __syncthreads();

  const int arow = 32 * wv + ch;              // A row (= this lane's point)
  const int koff = 8 * (lane >> 5);           // k base within 16-wide step
  const int swB = (ch & 7) << 3;              // W2T read swizzle (u16 units)
  const int swA = (arow & 7) << 2;            // h1p read swizzle (u32 units)
  // hoist loop-invariant BN1 scalars + W1T fragments into registers
  const float a10 = a1s[ch], b10 = b1s[ch];
  const float a11 = a1s[32 + ch], b11 = b1s[32 + ch];
  const bfrag w1h0 = *(const bfrag*)&W1Thi[ch][koff];
  const bfrag w1l0 = *(const bfrag*)&W1Tlo[ch][koff];
  const bfrag w1h1 = *(const bfrag*)&W1Thi[32 + ch][koff];
  const bfrag w1l1 = *(const bfrag*)&W1Tlo[32 + ch][koff];

  float psum = 0.0f, psq = 0.0f;

  // prefetched inputs (this wave's pillar only; halves duplicate points)
  int bb0 = blockIdx.x;
  float4 v = vox[bb0 * CHUNK + 32 * wv + ch];
  int4 cc = coords[bb0 * 4 + wv];
  int np = npnts[bb0 * 4 + wv];

  for (int bb = bb0; bb < NBATCH; bb += SB) {
    // ---- f for this lane's point
    float z = v.z;
#pragma unroll
    for (int s = 1; s < 64; s <<= 1) z += __shfl_xor(z, s, 64);  // 2x duplicated sum
    const float zc = z * (1.0f / 64.0f);
    float f[9];
    make_f(v, cc, np, ch, zc, f);

    // ---- prefetch next iteration's inputs (consumed above)
    {
      const int bbn = bb + SB;
      const int bbs = (bbn < NBATCH) ? bbn : bb;
      v = vox[bbs * CHUNK + 32 * wv + ch];
      cc = coords[bbs * 4 + wv];
      np = npnts[bbs * 4 + wv];
    }

    // ---- build phase-A A-fragments IN-REGISTER (lane-local; no LDS):
    // lanes<32 carry k=0..7 (f[0..7]); lanes>=32 carry k=8..15 (f[8],0,...,0)
    bfrag fa_hi, fa_lo;
    {
      unsigned int ahw[4] = {0u, 0u, 0u, 0u}, alw[4] = {0u, 0u, 0u, 0u};
#pragma unroll
      for (int e = 0; e < 8; ++e) {
        const float x = (lane < 32) ? f[e] : ((e == 0) ? f[8] : 0.0f);
        const unsigned int b = __float_as_uint(x);
        const float r = x - __uint_as_float(b & 0xFFFF0000u);
        ahw[e >> 1] |= (b >> 16) << ((e & 1) * 16);
        alw[e >> 1] |= (__float_as_uint(r) >> 16) << ((e & 1) * 16);
      }
      union U { unsigned int u[4]; bfrag b; };
      U ch_, cl_;
      ch_.u[0] = ahw[0]; ch_.u[1] = ahw[1]; ch_.u[2] = ahw[2]; ch_.u[3] = ahw[3];
      cl_.u[0] = alw[0]; cl_.u[1] = alw[1]; cl_.u[2] = alw[2]; cl_.u[3] = alw[3];
      fa_hi = ch_.b; fa_lo = cl_.b;
    }

    // ---- phase A: y1 = f @ W1 (one k-step, 3 split terms, 2 channel tiles)
    f32x16 yA0, yA1;
#pragma unroll
    for (int i = 0; i < 16; ++i) { yA0[i] = 0.0f; yA1[i] = 0.0f; }
    yA0 = __builtin_amdgcn_mfma_f32_32x32x16_bf16(fa_hi, w1h0, yA0, 0, 0, 0);
    yA1 = __builtin_amdgcn_mfma_f32_32x32x16_bf16(fa_hi, w1h1, yA1, 0, 0, 0);
    yA0 = __builtin_amdgcn_mfma_f32_32x32x16_bf16(fa_hi, w1l0, yA0, 0, 0, 0);
    yA1 = __builtin_amdgcn_mfma_f32_32x32x16_bf16(fa_hi, w1l1, yA1, 0, 0, 0);
    yA0 = __builtin_amdgcn_mfma_f32_32x32x16_bf16(fa_lo, w1h0, yA0, 0, 0, 0);
    yA1 = __builtin_amdgcn_mfma_f32_32x32x16_bf16(fa_lo, w1h1, yA1, 0, 0, 0);

    // ---- BN1 + relu + packed u32 writeback (C: col=ch, row=(reg&3)+8*(reg>>2)+4*(lane>>5))
    const int rbase = 4 * (lane >> 5);
#pragma unroll
    for (int reg = 0; reg < 16; ++reg) {
      const int pt = (reg & 3) + 8 * (reg >> 2) + rbase;
      const int row = 32 * wv + pt;
      const int swz = (pt & 7) << 2;    // u32 units
      {
        const float h = fmaxf(fmaf(yA0[reg], a10, b10), 0.0f);
        const unsigned int b = __float_as_uint(h);
        const float r = h - __uint_as_float(b & 0xFFFF0000u);
        h1p[row][ch ^ swz] = (__float_as_uint(r) & 0xFFFF0000u) | (b >> 16);
      }
      {
        const float h = fmaxf(fmaf(yA1[reg], a11, b11), 0.0f);
        const unsigned int b = __float_as_uint(h);
        const float r = h - __uint_as_float(b & 0xFFFF0000u);
        h1p[row][(32 + ch) ^ swz] = (__float_as_uint(r) & 0xFFFF0000u) | (b >> 16);
      }
    }
    // no barrier: wave wrote rows 32wv..32wv+31 and reads only those
    // (within-wave DS ordering)

    // ---- phase B: y2 = h1 @ W2 (4 k-steps, 3 split terms, 2 channel tiles)
    f32x16 acc0, acc1;
#pragma unroll
    for (int i = 0; i < 16; ++i) { acc0[i] = 0.0f; acc1[i] = 0.0f; }
#pragma unroll
    for (int ks = 0; ks < 4; ++ks) {
      const int kk = koff + 16 * ks;    // multiple of 8
      const uint4 pa0 = *(const uint4*)&h1p[arow][(kk) ^ swA];
      const uint4 pa1 = *(const uint4*)&h1p[arow][(kk + 4) ^ swA];
      union U { unsigned int u[4]; bfrag b; };
      U uh, ul;
      uh.u[0] = ((pa0.y & 0xFFFFu) << 16) | (pa0.x & 0xFFFFu);
      uh.u[1] = ((pa0.w & 0xFFFFu) << 16) | (pa0.z & 0xFFFFu);
      uh.u[2] = ((pa1.y & 0xFFFFu) << 16) | (pa1.x & 0xFFFFu);
      uh.u[3] = ((pa1.w & 0xFFFFu) << 16) | (pa1.z & 0xFFFFu);
      ul.u[0] = (pa0.y & 0xFFFF0000u) | (pa0.x >> 16);
      ul.u[1] = (pa0.w & 0xFFFF0000u) | (pa0.z >> 16);
      ul.u[2] = (pa1.y & 0xFFFF0000u) | (pa1.x >> 16);
      ul.u[3] = (pa1.w & 0xFFFF0000u) | (pa1.z >> 16);
      const bfrag ahi = uh.b, alo = ul.b;
      const bfrag bhi0 = *(const bfrag*)&W2Thi[ch][kk ^ swB];
      const bfrag blo0 = *(const bfrag*)&W2Tlo[ch][kk ^ swB];
      const bfrag bhi1 = *(const bfrag*)&W2Thi[32 + ch][kk ^ swB];
      const bfrag blo1 = *(const bfrag*)&W2Tlo[32 + ch][kk ^ swB];
      acc0 = __builtin_amdgcn_mfma_f32_32x32x16_bf16(ahi, bhi0, acc0, 0, 0, 0);
      acc1 = __builtin_amdgcn_mfma_f32_32x32x16_bf16(ahi, bhi1, acc1, 0, 0, 0);
      acc0 = __builtin_amdgcn_mfma_f32_32x32x16_bf16(ahi, blo0, acc0, 0, 0, 0);
      acc1 = __builtin_amdgcn_mfma_f32_32x32x16_bf16(ahi, blo1, acc1, 0, 0, 0);
      acc0 = __builtin_amdgcn_mfma_f32_32x32x16_bf16(alo, bhi0, acc0, 0, 0, 0);
      acc1 = __builtin_amdgcn_mfma_f32_32x32x16_bf16(alo, bhi1, acc1, 0, 0, 0);
    }

    // ---- epilogue: rows=points in 16 regs + partner lane (lane^32)
    float s0 = 0, q0 = 0, m0 = -INFINITY, s1 = 0, q1 = 0, m1 = -INFINITY;
#pragma unroll
    for (int i = 0; i < 16; ++i) {
      const float v0 = acc0[i], v1 = acc1[i];
      s0 += v0; q0 = fmaf(v0, v0, q0); m0 = fmaxf(m0, v0 * sg0);
      s1 += v1; q1 = fmaf(v1, v1, q1); m1 = fmaxf(m1, v1 * sg1);
    }
    s0 += __shfl_xor(s0, 32, 64); q0 += __shfl_xor(q0, 32, 64);
    m0 = fmaxf(m0, __shfl_xor(m0, 32, 64));
    s1 += __shfl_xor(s1, 32, 64); q1 += __shfl_xor(q1, 32, 64);
    m1 = fmaxf(m1, __shfl_xor(m1, 32, 64));
    const bool hiHalf = lane >= 32;   // lane's own channel = lane
    psum += hiHalf ? s1 : s0;
    psq += hiHalf ? q1 : q0;
    Y2SEL[(bb * 4 + wv) * 64 + lane] = hiHalf ? m1 : m0;   // coalesced
  }

  // block reduction: alias red arrays onto dead W1T staging (barrier-separated)
  __syncthreads();
  float* redS = (float*)&W1Thi[0][0];   // 256 floats fit in 2048 B
  float* redQ = (float*)&W1Tlo[0][0];
  redS[wv * 64 + lane] = psum;
  redQ[wv * 64 + lane] = psq;
  __syncthreads();
  if (t < 64) {
    const float s = redS[t] + redS[64 + t] + redS[128 + t] + redS[192 + t];
    const float q = redQ[t] + redQ[64 + t] + redQ[128 + t] + redQ[192 + t];
    P2[t * SB + blockIdx.x] = s;
    P2[(64 + t) * SB + blockIdx.x] = q;
  }
}

// ------------------------------------------------- finalize layer-2 BN params

__global__ void k_fin2(const double* __restrict__ T2, const float* __restrict__ g2,
                       const float* __restrict__ b2, float* __restrict__ params) {
  const int c = threadIdx.x;  // 64
  const double mean = T2[c] / (double)NPTS;
  const double var = T2[64 + c] / (double)NPTS - mean * mean;
  const double a = (double)g2[c] / sqrt(var + 0.001);
  params[128 + c] = (float)a;
  params[192 + c] = (float)((double)b2[c] - mean * a);
}

// ------------------------------------------------- K5: final output pass.

__global__ __launch_bounds__(256) void k_final(
    const float* __restrict__ params, const float* __restrict__ Y2SEL,
    float* __restrict__ out) {
  const int idx = blockIdx.x * 256 + threadIdx.x;   // NPIL*64 total
  const int c = idx & 63;
  const float a2 = params[128 + c];
  const float b2 = params[192 + c];
  const float v = Y2SEL[idx];
  const float sel = (a2 >= 0.0f) ? v : -v;
  out[idx] = fmaxf(fmaf(sel, a2, b2), 0.0f);
}

// ---------------------------------------------------------------- launch

extern "C" void kernel_launch(void* const* d_in, const int* in_sizes, int n_in,
                              void* d_out, int out_size, void* d_ws, size_t ws_size,
                              hipStream_t stream) {
  const float4* vox = (const float4*)d_in[0];
  const int4* coords = (const int4*)d_in[1];
  const int* npnts = (const int*)d_in[2];
  const float* W1 = (const float*)d_in[3];
  const float* g1 = (const float*)d_in[4];
  const float* b1 = (const float*)d_in[5];
  const float* W2 = (const float*)d_in[6];
  const float* g2 = (const float*)d_in[7];
  const float* b2 = (const float*)d_in[8];
  float* out = (float*)d_out;

  char* w = (char*)d_ws;
  size_t off = 0;
  double* T1 = (double*)(w + off); off += 512;                 // 54 doubles
  double* T2 = (double*)(w + off); off += 1024;                // 128 doubles
  float* P1 = (float*)(w + off); off += NMOM * K1_BLOCKS * 4;  // 324 KB
  float* P2 = (float*)(w + off); off += 128 * SB * 4;          // 393 KB
  float* params = (float*)(w + off); off += 256 * 4;           // 256 f32
  float* Y2SEL = (float*)(w + off); off += (size_t)NPIL * 64 * 4;  // 12.3 MB

  k_moments<<<K1_BLOCKS, 256, 0, stream>>>(vox, coords, npnts, P1);
  k_rowreduce<<<NMOM, 256, 0, stream>>>(P1, T1, K1_BLOCKS);
  k_fin1<<<1, 64, 0, stream>>>(T1, W1, g1, b1, params);
  k_stats2<<<SB, 256, 0, stream>>>(vox, coords, npnts, W1, W2, g2, params, P2, Y2SEL);
  k_rowreduce<<<128, 256, 0, stream>>>(P2, T2, SB);
  k_fin2<<<1, 64, 0, stream>>>(T2, g2, b2, params);
  k_final<<<(NPIL * 64) / 256, 256, 0, stream>>>(params, Y2SEL, out);
}

// Round 18
// 112.233 us; speedup vs baseline: 1.0748x; 1.0748x over previous
//
#include <hip/hip_runtime.h>
#include <math.h>

#define NB 4
#define NPI 12000
#define NM 32
#define NPTS (NB*NPI*NM)      // 1536000
#define NPIL (NB*NPI)         // 48000

// k_moments config
#define K1_BLOCKS 1500
#define K1_STRIDE (K1_BLOCKS*256)   // 384000
#define K1_ITERS 4                  // NPTS / K1_STRIDE
#define NMOM 54                     // 9 Sf + 45 Sff

// heavy-kernel config
#define CHUNK 128
#define NBATCH (NPTS/CHUNK)   // 12000
#define SB 768                // 3 blocks/CU x 256 CU resident (LDS 48KB)

typedef __attribute__((ext_vector_type(8))) short bfrag;     // 8 bf16 = 4 VGPRs
typedef __attribute__((ext_vector_type(16))) float f32x16;   // MFMA 32x32 acc

// ---------------------------------------------------------------- helpers

__device__ __forceinline__ void make_f(float4 v, int4 cc, int np, int m, float zc, float f[9]) {
  const float cx = ((float)cc.w + 0.5f) * 0.16f + 0.0f;
  const float cy = ((float)cc.z + 0.5f) * 0.16f - 39.68f;
  f[0] = v.x; f[1] = v.y; f[2] = v.z; f[3] = v.w;
  f[4] = v.x - cx; f[5] = v.y - cy; f[6] = cx; f[7] = cy; f[8] = zc;
  const float msk = (m < np) ? 1.0f : 0.0f;
#pragma unroll
  for (int i = 0; i < 9; ++i) f[i] *= msk;
}

// ------------------------------------------------- K1: f-moments

__global__ __launch_bounds__(256) void k_moments(
    const float4* __restrict__ vox, const int4* __restrict__ coords,
    const int* __restrict__ npnts, float* __restrict__ P1) {
  const int t = blockIdx.x * 256 + threadIdx.x;
  float acc[NMOM];
#pragma unroll
  for (int v = 0; v < NMOM; ++v) acc[v] = 0.0f;

#pragma unroll
  for (int j = 0; j < K1_ITERS; ++j) {
    const int pt = t + j * K1_STRIDE;
    const int pil = pt >> 5;
    const int m = pt & 31;
    const float4 v = vox[pt];
    const int4 cc = coords[pil];
    const int np = npnts[pil];
    float z = v.z;
#pragma unroll
    for (int s = 1; s < 32; s <<= 1) z += __shfl_xor(z, s, 32);
    const float zc = z * (1.0f / 32.0f);
    float f[9];
    make_f(v, cc, np, m, zc, f);
    int vi = 0;
#pragma unroll
    for (int i = 0; i < 9; ++i) acc[vi++] += f[i];
#pragma unroll
    for (int i = 0; i < 9; ++i)
#pragma unroll
      for (int jj = i; jj < 9; ++jj) acc[vi++] += f[i] * f[jj];
  }

#pragma unroll
  for (int v = 0; v < NMOM; ++v) {
    float x = acc[v];
#pragma unroll
    for (int s = 1; s < 64; s <<= 1) x += __shfl_xor(x, s, 64);
    acc[v] = x;
  }
  __shared__ float red[4][NMOM];
  const int wave = threadIdx.x >> 6, lane = threadIdx.x & 63;
  if (lane == 0) {
#pragma unroll
    for (int v = 0; v < NMOM; ++v) red[wave][v] = acc[v];
  }
  __syncthreads();
  if (threadIdx.x < NMOM) {
    float s = red[0][threadIdx.x] + red[1][threadIdx.x] + red[2][threadIdx.x] + red[3][threadIdx.x];
    P1[threadIdx.x * K1_BLOCKS + blockIdx.x] = s;
  }
}

// ------------------------------------------------- generic row reduce (f32 -> f64)

__global__ __launch_bounds__(256) void k_rowreduce(
    const float* __restrict__ src, double* __restrict__ dst, int ncols) {
  const int row = blockIdx.x;
  const float* p = src + row * ncols;
  double sd = 0.0;
  for (int i = threadIdx.x; i < ncols; i += 256) sd += (double)p[i];
#pragma unroll
  for (int s = 1; s < 64; s <<= 1) sd += __shfl_xor(sd, s, 64);
  __shared__ double rd[4];
  const int wave = threadIdx.x >> 6, lane = threadIdx.x & 63;
  if (lane == 0) rd[wave] = sd;
  __syncthreads();
  if (threadIdx.x == 0) dst[row] = rd[0] + rd[1] + rd[2] + rd[3];
}

// ------------------------------------------------- finalize layer-1 BN params

__global__ void k_fin1(const double* __restrict__ T1, const float* __restrict__ W1,
                       const float* __restrict__ g1, const float* __restrict__ b1,
                       float* __restrict__ params) {
  const int c = threadIdx.x;  // 64
  double w[9];
#pragma unroll
  for (int i = 0; i < 9; ++i) w[i] = (double)W1[i * 64 + c];
  double mean = 0.0;
#pragma unroll
  for (int i = 0; i < 9; ++i) mean += w[i] * T1[i];
  mean /= (double)NPTS;
  double e2 = 0.0;
  int v = 9;
#pragma unroll
  for (int i = 0; i < 9; ++i)
#pragma unroll
    for (int j = i; j < 9; ++j) {
      const double t = T1[v++] * w[i] * w[j];
      e2 += (i == j) ? t : 2.0 * t;
    }
  e2 /= (double)NPTS;
  const double var = e2 - mean * mean;
  const double a = (double)g1[c] / sqrt(var + 0.001);
  params[c] = (float)a;
  params[64 + c] = (float)((double)b1[c] - mean * a);
}

// ------------------------------------------------- K3: both layers via MFMA, v4
// v3 (R17) post-mortem: 3rd block/CU didn't fit (53760x3 + driver reserve >
// 160KB) -> 2-block residency + ragged cohorts; and the 64 per-reg swizzled
// ds_write addr computations were ~half the VALU. v4:
// (1) LDS = 49152 B exactly (3x48KB = 144KB): W1T/a1s/b1s staging aliased
//     INSIDE h1p (consumed into regs before loop; extra barrier guards the
//     overwrite). redS/redQ alias post-loop as before.
// (2) Writeback uses 4 base addresses + compile-time byte offsets
//     (q*2048 + {0,128}): pt&7 = (j+rbase)&7 is constant per j, so the XOR
//     swizzle folds into the base -> ds_write offset: immediates.
// Math/layout byte-identical to R17 (refcheck-proven).

__global__ __launch_bounds__(256) void k_stats2(
    const float4* __restrict__ vox, const int4* __restrict__ coords,
    const int* __restrict__ npnts, const float* __restrict__ W1,
    const float* __restrict__ W2, const float* __restrict__ g2,
    const float* __restrict__ params, float* __restrict__ P2,
    float* __restrict__ Y2SEL) {
  __shared__ __align__(16) unsigned int smem[12288];   // 49152 B total
  unsigned int* h1p = smem;                                  // [128][64] u32 (swz)
  unsigned short* W2Thi = (unsigned short*)(smem + 8192);    // [64][64] (swz)
  unsigned short* W2Tlo = (unsigned short*)(smem + 10240);   // [64][64] (swz)
  // init-only aliases inside the h1p region (dead after reg-hoist + barrier):
  unsigned short* W1Thi = (unsigned short*)smem;             // [64][16]
  unsigned short* W1Tlo = (unsigned short*)(smem + 512);     // [64][16]
  float* a1s = (float*)(smem + 1024);                        // [64]
  float* b1s = (float*)(smem + 1088);                        // [64]

  const int t = threadIdx.x;
  if (t < 64) { a1s[t] = params[t]; b1s[t] = params[64 + t]; }
  // stage W1^T split (k padded 9->16): W1T[ch][k]
  for (int i = t; i < 1024; i += 256) {
    const int c = i >> 4, k = i & 15;
    const float x = (k < 9) ? W1[k * 64 + c] : 0.0f;
    const unsigned int b = __float_as_uint(x);
    W1Thi[c * 16 + k] = (unsigned short)(b >> 16);
    const float r = x - __uint_as_float(b & 0xFFFF0000u);
    W1Tlo[c * 16 + k] = (unsigned short)(__float_as_uint(r) >> 16);
  }
  // stage W2^T split, swizzled: element (ch,k) at col k ^ ((ch&7)<<3)
  for (int i = t; i < 4096; i += 256) {
    const int k = i >> 6, c = i & 63;
    const float x = W2[i];
    const unsigned int b = __float_as_uint(x);
    const float r = x - __uint_as_float(b & 0xFFFF0000u);
    const int kc = k ^ ((c & 7) << 3);
    W2Thi[c * 64 + kc] = (unsigned short)(b >> 16);
    W2Tlo[c * 64 + kc] = (unsigned short)(__float_as_uint(r) >> 16);
  }

  const int lane = t & 63;
  const int wv = t >> 6;                      // wave owns pillar wv of each batch
  const int ch = lane & 31;                   // tile-local channel / point id
  const float sg0 = (g2[ch] >= 0.0f) ? 1.0f : -1.0f;
  const float sg1 = (g2[32 + ch] >= 0.0f) ? 1.0f : -1.0f;
  __syncthreads();   // staging visible to all waves

  const int koff = 8 * (lane >> 5);           // k base within 16-wide step
  const int arow = 32 * wv + ch;              // A row (= this lane's point)
  const int swB = (ch & 7) << 3;              // W2T read swizzle (u16 units)
  const int swA = (arow & 7) << 2;            // h1p read swizzle (u32 units)
  // hoist loop-invariant BN1 scalars + W1T fragments into registers
  const float a10 = a1s[ch], b10 = b1s[ch];
  const float a11 = a1s[32 + ch], b11 = b1s[32 + ch];
  const bfrag w1h0 = *(const bfrag*)&W1Thi[ch * 16 + koff];
  const bfrag w1l0 = *(const bfrag*)&W1Tlo[ch * 16 + koff];
  const bfrag w1h1 = *(const bfrag*)&W1Thi[(32 + ch) * 16 + koff];
  const bfrag w1l1 = *(const bfrag*)&W1Tlo[(32 + ch) * 16 + koff];
  __syncthreads();   // ALL waves done reading staging before h1p overwrite

  float psum = 0.0f, psq = 0.0f;

  // prefetched inputs (this wave's pillar only; halves duplicate points)
  int bb0 = blockIdx.x;
  float4 v = vox[bb0 * CHUNK + 32 * wv + ch];
  int4 cc = coords[bb0 * 4 + wv];
  int np = npnts[bb0 * 4 + wv];

  for (int bb = bb0; bb < NBATCH; bb += SB) {
    // ---- f for this lane's point
    float z = v.z;
#pragma unroll
    for (int s = 1; s < 64; s <<= 1) z += __shfl_xor(z, s, 64);  // 2x duplicated sum
    const float zc = z * (1.0f / 64.0f);
    float f[9];
    make_f(v, cc, np, ch, zc, f);

    // ---- prefetch next iteration's inputs (consumed above)
    {
      const int bbn = bb + SB;
      const int bbs = (bbn < NBATCH) ? bbn : bb;
      v = vox[bbs * CHUNK + 32 * wv + ch];
      cc = coords[bbs * 4 + wv];
      np = npnts[bbs * 4 + wv];
    }

    // ---- build phase-A A-fragments IN-REGISTER (lane-local; no LDS):
    // lanes<32 carry k=0..7 (f[0..7]); lanes>=32 carry k=8..15 (f[8],0,...,0)
    bfrag fa_hi, fa_lo;
    {
      unsigned int ahw[4] = {0u, 0u, 0u, 0u}, alw[4] = {0u, 0u, 0u, 0u};
#pragma unroll
      for (int e = 0; e < 8; ++e) {
        const float x = (lane < 32) ? f[e] : ((e == 0) ? f[8] : 0.0f);
        const unsigned int b = __float_as_uint(x);
        const float r = x - __uint_as_float(b & 0xFFFF0000u);
        ahw[e >> 1] |= (b >> 16) << ((e & 1) * 16);
        alw[e >> 1] |= (__float_as_uint(r) >> 16) << ((e & 1) * 16);
      }
      union U { unsigned int u[4]; bfrag b; };
      U ch_, cl_;
      ch_.u[0] = ahw[0]; ch_.u[1] = ahw[1]; ch_.u[2] = ahw[2]; ch_.u[3] = ahw[3];
      cl_.u[0] = alw[0]; cl_.u[1] = alw[1]; cl_.u[2] = alw[2]; cl_.u[3] = alw[3];
      fa_hi = ch_.b; fa_lo = cl_.b;
    }

    // ---- phase A: y1 = f @ W1 (one k-step, 3 split terms, 2 channel tiles)
    f32x16 yA0, yA1;
#pragma unroll
    for (int i = 0; i < 16; ++i) { yA0[i] = 0.0f; yA1[i] = 0.0f; }
    yA0 = __builtin_amdgcn_mfma_f32_32x32x16_bf16(fa_hi, w1h0, yA0, 0, 0, 0);
    yA1 = __builtin_amdgcn_mfma_f32_32x32x16_bf16(fa_hi, w1h1, yA1, 0, 0, 0);
    yA0 = __builtin_amdgcn_mfma_f32_32x32x16_bf16(fa_hi, w1l0, yA0, 0, 0, 0);
    yA1 = __builtin_amdgcn_mfma_f32_32x32x16_bf16(fa_hi, w1l1, yA1, 0, 0, 0);
    yA0 = __builtin_amdgcn_mfma_f32_32x32x16_bf16(fa_lo, w1h0, yA0, 0, 0, 0);
    yA1 = __builtin_amdgcn_mfma_f32_32x32x16_bf16(fa_lo, w1h1, yA1, 0, 0, 0);

    // ---- BN1 + relu + packed u32 writeback.
    // C layout: row(point) = (reg&3)+8*(reg>>2)+rbase, col = ch (+32 tile1).
    // reg = j + 4q -> row = rbase+j+8q, swz = ((j+rbase)&7)<<2 (const per j):
    // 4 base addresses, all writes at byte offsets q*2048 + {0,128}.
    const int rbase = 4 * (lane >> 5);
#pragma unroll
    for (int j = 0; j < 4; ++j) {
      const int swzj = ((j + rbase) & 7) << 2;
      unsigned int* bp = &h1p[(32 * wv + rbase + j) * 64 + (ch ^ swzj)];
#pragma unroll
      for (int q = 0; q < 4; ++q) {
        const int reg = j + 4 * q;
        {
          const float h = fmaxf(fmaf(yA0[reg], a10, b10), 0.0f);
          const unsigned int b = __float_as_uint(h);
          const float r = h - __uint_as_float(b & 0xFFFF0000u);
          bp[q * 512] = (__float_as_uint(r) & 0xFFFF0000u) | (b >> 16);
        }
        {
          const float h = fmaxf(fmaf(yA1[reg], a11, b11), 0.0f);
          const unsigned int b = __float_as_uint(h);
          const float r = h - __uint_as_float(b & 0xFFFF0000u);
          bp[q * 512 + 32] = (__float_as_uint(r) & 0xFFFF0000u) | (b >> 16);
        }
      }
    }
    // no barrier: wave wrote rows 32wv..32wv+31 and reads only those
    // (within-wave DS ordering)

    // ---- phase B: y2 = h1 @ W2 (4 k-steps, 3 split terms, 2 channel tiles)
    f32x16 acc0, acc1;
#pragma unroll
    for (int i = 0; i < 16; ++i) { acc0[i] = 0.0f; acc1[i] = 0.0f; }
#pragma unroll
    for (int ks = 0; ks < 4; ++ks) {
      const int kk = koff + 16 * ks;    // multiple of 8
      const uint4 pa0 = *(const uint4*)&h1p[arow * 64 + ((kk) ^ swA)];
      const uint4 pa1 = *(const uint4*)&h1p[arow * 64 + ((kk + 4) ^ swA)];
      union U { unsigned int u[4]; bfrag b; };
      U uh, ul;
      uh.u[0] = ((pa0.y & 0xFFFFu) << 16) | (pa0.x & 0xFFFFu);
      uh.u[1] = ((pa0.w & 0xFFFFu) << 16) | (pa0.z & 0xFFFFu);
      uh.u[2] = ((pa1.y & 0xFFFFu) << 16) | (pa1.x & 0xFFFFu);
      uh.u[3] = ((pa1.w & 0xFFFFu) << 16) | (pa1.z & 0xFFFFu);
      ul.u[0] = (pa0.y & 0xFFFF0000u) | (pa0.x >> 16);
      ul.u[1] = (pa0.w & 0xFFFF0000u) | (pa0.z >> 16);
      ul.u[2] = (pa1.y & 0xFFFF0000u) | (pa1.x >> 16);
      ul.u[3] = (pa1.w & 0xFFFF0000u) | (pa1.z >> 16);
      const bfrag ahi = uh.b, alo = ul.b;
      const bfrag bhi0 = *(const bfrag*)&W2Thi[ch * 64 + (kk ^ swB)];
      const bfrag blo0 = *(const bfrag*)&W2Tlo[ch * 64 + (kk ^ swB)];
      const bfrag bhi1 = *(const bfrag*)&W2Thi[(32 + ch) * 64 + (kk ^ swB)];
      const bfrag blo1 = *(const bfrag*)&W2Tlo[(32 + ch) * 64 + (kk ^ swB)];
      acc0 = __builtin_amdgcn_mfma_f32_32x32x16_bf16(ahi, bhi0, acc0, 0, 0, 0);
      acc1 = __builtin_amdgcn_mfma_f32_32x32x16_bf16(ahi, bhi1, acc1, 0, 0, 0);
      acc0 = __builtin_amdgcn_mfma_f32_32x32x16_bf16(ahi, blo0, acc0, 0, 0, 0);
      acc1 = __builtin_amdgcn_mfma_f32_32x32x16_bf16(ahi, blo1, acc1, 0, 0, 0);
      acc0 = __builtin_amdgcn_mfma_f32_32x32x16_bf16(alo, bhi0, acc0, 0, 0, 0);
      acc1 = __builtin_amdgcn_mfma_f32_32x32x16_bf16(alo, bhi1, acc1, 0, 0, 0);
    }

    // ---- epilogue: rows=points in 16 regs + partner lane (lane^32)
    float s0 = 0, q0 = 0, m0 = -INFINITY, s1 = 0, q1 = 0, m1 = -INFINITY;
#pragma unroll
    for (int i = 0; i < 16; ++i) {
      const float v0 = acc0[i], v1 = acc1[i];
      s0 += v0; q0 = fmaf(v0, v0, q0); m0 = fmaxf(m0, v0 * sg0);
      s1 += v1; q1 = fmaf(v1, v1, q1); m1 = fmaxf(m1, v1 * sg1);
    }
    s0 += __shfl_xor(s0, 32, 64); q0 += __shfl_xor(q0, 32, 64);
    m0 = fmaxf(m0, __shfl_xor(m0, 32, 64));
    s1 += __shfl_xor(s1, 32, 64); q1 += __shfl_xor(q1, 32, 64);
    m1 = fmaxf(m1, __shfl_xor(m1, 32, 64));
    const bool hiHalf = lane >= 32;   // lane's own channel = lane
    psum += hiHalf ? s1 : s0;
    psq += hiHalf ? q1 : q0;
    Y2SEL[(bb * 4 + wv) * 64 + lane] = hiHalf ? m1 : m0;   // coalesced
  }

  // block reduction: alias red arrays onto h1p region (barrier-separated)
  __syncthreads();
  float* redS = (float*)smem;           // 256 floats
  float* redQ = (float*)(smem + 256);   // 256 floats
  redS[wv * 64 + lane] = psum;
  redQ[wv * 64 + lane] = psq;
  __syncthreads();
  if (t < 64) {
    const float s = redS[t] + redS[64 + t] + redS[128 + t] + redS[192 + t];
    const float q = redQ[t] + redQ[64 + t] + redQ[128 + t] + redQ[192 + t];
    P2[t * SB + blockIdx.x] = s;
    P2[(64 + t) * SB + blockIdx.x] = q;
  }
}

// ------------------------------------------------- finalize layer-2 BN params

__global__ void k_fin2(const double* __restrict__ T2, const float* __restrict__ g2,
                       const float* __restrict__ b2, float* __restrict__ params) {
  const int c = threadIdx.x;  // 64
  const double mean = T2[c] / (double)NPTS;
  const double var = T2[64 + c] / (double)NPTS - mean * mean;
  const double a = (double)g2[c] / sqrt(var + 0.001);
  params[128 + c] = (float)a;
  params[192 + c] = (float)((double)b2[c] - mean * a);
}

// ------------------------------------------------- K5: final output pass.

__global__ __launch_bounds__(256) void k_final(
    const float* __restrict__ params, const float* __restrict__ Y2SEL,
    float* __restrict__ out) {
  const int idx = blockIdx.x * 256 + threadIdx.x;   // NPIL*64 total
  const int c = idx & 63;
  const float a2 = params[128 + c];
  const float b2 = params[192 + c];
  const float v = Y2SEL[idx];
  const float sel = (a2 >= 0.0f) ? v : -v;
  out[idx] = fmaxf(fmaf(sel, a2, b2), 0.0f);
}

// ---------------------------------------------------------------- launch

extern "C" void kernel_launch(void* const* d_in, const int* in_sizes, int n_in,
                              void* d_out, int out_size, void* d_ws, size_t ws_size,
                              hipStream_t stream) {
  const float4* vox = (const float4*)d_in[0];
  const int4* coords = (const int4*)d_in[1];
  const int* npnts = (const int*)d_in[2];
  const float* W1 = (const float*)d_in[3];
  const float* g1 = (const float*)d_in[4];
  const float* b1 = (const float*)d_in[5];
  const float* W2 = (const float*)d_in[6];
  const float* g2 = (const float*)d_in[7];
  const float* b2 = (const float*)d_in[8];
  float* out = (float*)d_out;

  char* w = (char*)d_ws;
  size_t off = 0;
  double* T1 = (double*)(w + off); off += 512;                 // 54 doubles
  double* T2 = (double*)(w + off); off += 1024;                // 128 doubles
  float* P1 = (float*)(w + off); off += NMOM * K1_BLOCKS * 4;  // 324 KB
  float* P2 = (float*)(w + off); off += 128 * SB * 4;          // 393 KB
  float* params = (float*)(w + off); off += 256 * 4;           // 256 f32
  float* Y2SEL = (float*)(w + off); off += (size_t)NPIL * 64 * 4;  // 12.3 MB

  k_moments<<<K1_BLOCKS, 256, 0, stream>>>(vox, coords, npnts, P1);
  k_rowreduce<<<NMOM, 256, 0, stream>>>(P1, T1, K1_BLOCKS);
  k_fin1<<<1, 64, 0, stream>>>(T1, W1, g1, b1, params);
  k_stats2<<<SB, 256, 0, stream>>>(vox, coords, npnts, W1, W2, g2, params, P2, Y2SEL);
  k_rowreduce<<<128, 256, 0, stream>>>(P2, T2, SB);
  k_fin2<<<1, 64, 0, stream>>>(T2, g2, b2, params);
  k_final<<<(NPIL * 64) / 256, 256, 0, stream>>>(params, Y2SEL, out);
}

// Round 19
// 110.789 us; speedup vs baseline: 1.0888x; 1.0130x over previous
//
#include <hip/hip_runtime.h>
#include <math.h>

#define NB 4
#define NPI 12000
#define NM 32
#define NPTS (NB*NPI*NM)      // 1536000
#define NPIL (NB*NPI)         // 48000

// k_moments config
#define K1_BLOCKS 1500
#define K1_STRIDE (K1_BLOCKS*256)   // 384000
#define K1_ITERS 4                  // NPTS / K1_STRIDE
#define NMOM 54                     // 9 Sf + 45 Sff

// heavy-kernel config
#define CHUNK 128
#define NBATCH (NPTS/CHUNK)   // 12000
#define SB 768                // 3 blocks/CU x 256 CU resident (LDS 48KB)

typedef __attribute__((ext_vector_type(8))) short bfrag;     // 8 bf16 = 4 VGPRs
typedef __attribute__((ext_vector_type(16))) float f32x16;   // MFMA 32x32 acc

// ---------------------------------------------------------------- helpers

__device__ __forceinline__ void make_f(float4 v, int4 cc, int np, int m, float zc, float f[9]) {
  const float cx = ((float)cc.w + 0.5f) * 0.16f + 0.0f;
  const float cy = ((float)cc.z + 0.5f) * 0.16f - 39.68f;
  f[0] = v.x; f[1] = v.y; f[2] = v.z; f[3] = v.w;
  f[4] = v.x - cx; f[5] = v.y - cy; f[6] = cx; f[7] = cy; f[8] = zc;
  const float msk = (m < np) ? 1.0f : 0.0f;
#pragma unroll
  for (int i = 0; i < 9; ++i) f[i] *= msk;
}

// ------------------------------------------------- K1: f-moments

__global__ __launch_bounds__(256) void k_moments(
    const float4* __restrict__ vox, const int4* __restrict__ coords,
    const int* __restrict__ npnts, float* __restrict__ P1) {
  const int t = blockIdx.x * 256 + threadIdx.x;
  float acc[NMOM];
#pragma unroll
  for (int v = 0; v < NMOM; ++v) acc[v] = 0.0f;

#pragma unroll
  for (int j = 0; j < K1_ITERS; ++j) {
    const int pt = t + j * K1_STRIDE;
    const int pil = pt >> 5;
    const int m = pt & 31;
    const float4 v = vox[pt];
    const int4 cc = coords[pil];
    const int np = npnts[pil];
    float z = v.z;
#pragma unroll
    for (int s = 1; s < 32; s <<= 1) z += __shfl_xor(z, s, 32);
    const float zc = z * (1.0f / 32.0f);
    float f[9];
    make_f(v, cc, np, m, zc, f);
    int vi = 0;
#pragma unroll
    for (int i = 0; i < 9; ++i) acc[vi++] += f[i];
#pragma unroll
    for (int i = 0; i < 9; ++i)
#pragma unroll
      for (int jj = i; jj < 9; ++jj) acc[vi++] += f[i] * f[jj];
  }

#pragma unroll
  for (int v = 0; v < NMOM; ++v) {
    float x = acc[v];
#pragma unroll
    for (int s = 1; s < 64; s <<= 1) x += __shfl_xor(x, s, 64);
    acc[v] = x;
  }
  __shared__ float red[4][NMOM];
  const int wave = threadIdx.x >> 6, lane = threadIdx.x & 63;
  if (lane == 0) {
#pragma unroll
    for (int v = 0; v < NMOM; ++v) red[wave][v] = acc[v];
  }
  __syncthreads();
  if (threadIdx.x < NMOM) {
    float s = red[0][threadIdx.x] + red[1][threadIdx.x] + red[2][threadIdx.x] + red[3][threadIdx.x];
    P1[threadIdx.x * K1_BLOCKS + blockIdx.x] = s;
  }
}

// ------------------------------------------------- generic row reduce (f32 -> f64)

__global__ __launch_bounds__(256) void k_rowreduce(
    const float* __restrict__ src, double* __restrict__ dst, int ncols) {
  const int row = blockIdx.x;
  const float* p = src + row * ncols;
  double sd = 0.0;
  for (int i = threadIdx.x; i < ncols; i += 256) sd += (double)p[i];
#pragma unroll
  for (int s = 1; s < 64; s <<= 1) sd += __shfl_xor(sd, s, 64);
  __shared__ double rd[4];
  const int wave = threadIdx.x >> 6, lane = threadIdx.x & 63;
  if (lane == 0) rd[wave] = sd;
  __syncthreads();
  if (threadIdx.x == 0) dst[row] = rd[0] + rd[1] + rd[2] + rd[3];
}

// ------------------------------------------------- finalize layer-1 BN params

__global__ void k_fin1(const double* __restrict__ T1, const float* __restrict__ W1,
                       const float* __restrict__ g1, const float* __restrict__ b1,
                       float* __restrict__ params) {
  const int c = threadIdx.x;  // 64
  double w[9];
#pragma unroll
  for (int i = 0; i < 9; ++i) w[i] = (double)W1[i * 64 + c];
  double mean = 0.0;
#pragma unroll
  for (int i = 0; i < 9; ++i) mean += w[i] * T1[i];
  mean /= (double)NPTS;
  double e2 = 0.0;
  int v = 9;
#pragma unroll
  for (int i = 0; i < 9; ++i)
#pragma unroll
    for (int j = i; j < 9; ++j) {
      const double t = T1[v++] * w[i] * w[j];
      e2 += (i == j) ? t : 2.0 * t;
    }
  e2 /= (double)NPTS;
  const double var = e2 - mean * mean;
  const double a = (double)g1[c] / sqrt(var + 0.001);
  params[c] = (float)a;
  params[64 + c] = (float)((double)b1[c] - mean * a);
}

// ------------------------------------------------- K3: both layers via MFMA, v5
// R18 post-mortem: VALU-bound (65% busy = 45 of 71 us). v5 cuts VALU + W2
// read conflicts without touching the proven dataflow:
// (1) BN1 folded into the GEMM: W1aug[k<9] = W1*diag(a1), W1aug[9] = b1adj,
//     f_aug[9] = 1.0 ALWAYS (not masked) -> masked rows give relu(b1adj)
//     exactly as the reference. Kills the per-value BN1 fmaf + a1s/b1s.
// (2) Loop-invariant zero16 as C of each chain's first MFMA -> no per-iter
//     accumulator zeroing.
// (3) W2T interleaved [64][128] u16 (256B rows, hi at col k^sw, lo at
//     (64+k)^sw, sw=(ch&15)<<3): 16 16B-slots/row -> W2 b128 reads 4-way ->
//     2-way (free). Staged once outside the loop.

__global__ __launch_bounds__(256) void k_stats2(
    const float4* __restrict__ vox, const int4* __restrict__ coords,
    const int* __restrict__ npnts, const float* __restrict__ W1,
    const float* __restrict__ W2, const float* __restrict__ g2,
    const float* __restrict__ params, float* __restrict__ P2,
    float* __restrict__ Y2SEL) {
  __shared__ __align__(16) unsigned int smem[12288];   // 49152 B total
  unsigned int* h1p = smem;                                  // [128][64] u32 (swz)
  unsigned short* W2T = (unsigned short*)(smem + 8192);      // [64][128] u16 interleaved (swz)
  // init-only aliases inside the h1p region (dead after reg-hoist + barrier):
  unsigned short* W1Thi = (unsigned short*)smem;             // [64][16]
  unsigned short* W1Tlo = (unsigned short*)(smem + 512);     // [64][16]

  const int t = threadIdx.x;
  // stage W1aug^T split (k padded 10->16): k<9: W1[k][c]*a1[c]; k==9: b1adj[c]
  for (int i = t; i < 1024; i += 256) {
    const int c = i >> 4, k = i & 15;
    float x;
    if (k < 9)       x = W1[k * 64 + c] * params[c];
    else if (k == 9) x = params[64 + c];
    else             x = 0.0f;
    const unsigned int b = __float_as_uint(x);
    W1Thi[c * 16 + k] = (unsigned short)(b >> 16);
    const float r = x - __uint_as_float(b & 0xFFFF0000u);
    W1Tlo[c * 16 + k] = (unsigned short)(__float_as_uint(r) >> 16);
  }
  // stage W2^T split, interleaved+swizzled: hi(ch,k) at col k^sw, lo at (64+k)^sw
  for (int i = t; i < 4096; i += 256) {
    const int k = i >> 6, c = i & 63;
    const float x = W2[i];
    const unsigned int b = __float_as_uint(x);
    const float r = x - __uint_as_float(b & 0xFFFF0000u);
    const int sw = (c & 15) << 3;
    W2T[c * 128 + (k ^ sw)] = (unsigned short)(b >> 16);
    W2T[c * 128 + ((64 + k) ^ sw)] = (unsigned short)(__float_as_uint(r) >> 16);
  }

  const int lane = t & 63;
  const int wv = t >> 6;                      // wave owns pillar wv of each batch
  const int ch = lane & 31;                   // tile-local channel / point id
  const float sg0 = (g2[ch] >= 0.0f) ? 1.0f : -1.0f;
  const float sg1 = (g2[32 + ch] >= 0.0f) ? 1.0f : -1.0f;
  __syncthreads();   // staging visible to all waves

  const int koff = 8 * (lane >> 5);           // k base within 16-wide step
  const int arow = 32 * wv + ch;              // A row (= this lane's point)
  const int swB = (ch & 15) << 3;             // W2T read swizzle (u16 units)
  const int swA = (arow & 7) << 2;            // h1p read swizzle (u32 units)
  // hoist loop-invariant W1aug fragments into registers
  const bfrag w1h0 = *(const bfrag*)&W1Thi[ch * 16 + koff];
  const bfrag w1l0 = *(const bfrag*)&W1Tlo[ch * 16 + koff];
  const bfrag w1h1 = *(const bfrag*)&W1Thi[(32 + ch) * 16 + koff];
  const bfrag w1l1 = *(const bfrag*)&W1Tlo[(32 + ch) * 16 + koff];
  __syncthreads();   // ALL waves done reading W1T staging before h1p overwrite

  // loop-invariant zero accumulator (C operand of each chain's first MFMA)
  f32x16 zero16;
#pragma unroll
  for (int i = 0; i < 16; ++i) zero16[i] = 0.0f;

  float psum = 0.0f, psq = 0.0f;

  // prefetched inputs (this wave's pillar only; halves duplicate points)
  int bb0 = blockIdx.x;
  float4 v = vox[bb0 * CHUNK + 32 * wv + ch];
  int4 cc = coords[bb0 * 4 + wv];
  int np = npnts[bb0 * 4 + wv];

  for (int bb = bb0; bb < NBATCH; bb += SB) {
    // ---- f for this lane's point
    float z = v.z;
#pragma unroll
    for (int s = 1; s < 64; s <<= 1) z += __shfl_xor(z, s, 64);  // 2x duplicated sum
    const float zc = z * (1.0f / 64.0f);
    float f[9];
    make_f(v, cc, np, ch, zc, f);

    // ---- prefetch next iteration's inputs (consumed above)
    {
      const int bbn = bb + SB;
      const int bbs = (bbn < NBATCH) ? bbn : bb;
      v = vox[bbs * CHUNK + 32 * wv + ch];
      cc = coords[bbs * 4 + wv];
      np = npnts[bbs * 4 + wv];
    }

    // ---- build phase-A A-fragments IN-REGISTER (lane-local; no LDS):
    // lanes<32: k=0..7 (f[0..7]); lanes>=32: k=8..15 (f[8], 1.0, 0...)
    bfrag fa_hi, fa_lo;
    {
      unsigned int ahw[4] = {0u, 0u, 0u, 0u}, alw[4] = {0u, 0u, 0u, 0u};
#pragma unroll
      for (int e = 0; e < 8; ++e) {
        const float x = (lane < 32) ? f[e]
                        : ((e == 0) ? f[8] : (e == 1) ? 1.0f : 0.0f);
        const unsigned int b = __float_as_uint(x);
        const float r = x - __uint_as_float(b & 0xFFFF0000u);
        ahw[e >> 1] |= (b >> 16) << ((e & 1) * 16);
        alw[e >> 1] |= (__float_as_uint(r) >> 16) << ((e & 1) * 16);
      }
      union U { unsigned int u[4]; bfrag b; };
      U ch_, cl_;
      ch_.u[0] = ahw[0]; ch_.u[1] = ahw[1]; ch_.u[2] = ahw[2]; ch_.u[3] = ahw[3];
      cl_.u[0] = alw[0]; cl_.u[1] = alw[1]; cl_.u[2] = alw[2]; cl_.u[3] = alw[3];
      fa_hi = ch_.b; fa_lo = cl_.b;
    }

    // ---- phase A: y1aug = f_aug @ W1aug (one k-step, 3 split terms, 2 tiles)
    f32x16 yA0 = __builtin_amdgcn_mfma_f32_32x32x16_bf16(fa_hi, w1h0, zero16, 0, 0, 0);
    f32x16 yA1 = __builtin_amdgcn_mfma_f32_32x32x16_bf16(fa_hi, w1h1, zero16, 0, 0, 0);
    yA0 = __builtin_amdgcn_mfma_f32_32x32x16_bf16(fa_hi, w1l0, yA0, 0, 0, 0);
    yA1 = __builtin_amdgcn_mfma_f32_32x32x16_bf16(fa_hi, w1l1, yA1, 0, 0, 0);
    yA0 = __builtin_amdgcn_mfma_f32_32x32x16_bf16(fa_lo, w1h0, yA0, 0, 0, 0);
    yA1 = __builtin_amdgcn_mfma_f32_32x32x16_bf16(fa_lo, w1h1, yA1, 0, 0, 0);

    // ---- relu + packed u32 writeback (BN1 already folded into the GEMM).
    // C layout: row(point) = (reg&3)+8*(reg>>2)+rbase, col = ch (+32 tile1).
    const int rbase = 4 * (lane >> 5);
#pragma unroll
    for (int j = 0; j < 4; ++j) {
      const int swzj = ((j + rbase) & 7) << 2;
      unsigned int* bp = &h1p[(32 * wv + rbase + j) * 64 + (ch ^ swzj)];
#pragma unroll
      for (int q = 0; q < 4; ++q) {
        const int reg = j + 4 * q;
        {
          const float h = fmaxf(yA0[reg], 0.0f);
          const unsigned int b = __float_as_uint(h);
          const float r = h - __uint_as_float(b & 0xFFFF0000u);
          bp[q * 512] = (__float_as_uint(r) & 0xFFFF0000u) | (b >> 16);
        }
        {
          const float h = fmaxf(yA1[reg], 0.0f);
          const unsigned int b = __float_as_uint(h);
          const float r = h - __uint_as_float(b & 0xFFFF0000u);
          bp[q * 512 + 32] = (__float_as_uint(r) & 0xFFFF0000u) | (b >> 16);
        }
      }
    }
    // no barrier: wave wrote rows 32wv..32wv+31 and reads only those
    // (within-wave DS ordering)

    // ---- phase B: y2 = h1 @ W2 (4 k-steps, 3 split terms, 2 channel tiles)
    f32x16 acc0, acc1;
#pragma unroll
    for (int ks = 0; ks < 4; ++ks) {
      const int kk = koff + 16 * ks;    // multiple of 8
      const uint4 pa0 = *(const uint4*)&h1p[arow * 64 + ((kk) ^ swA)];
      const uint4 pa1 = *(const uint4*)&h1p[arow * 64 + ((kk + 4) ^ swA)];
      union U { unsigned int u[4]; bfrag b; };
      U uh, ul;
      uh.u[0] = ((pa0.y & 0xFFFFu) << 16) | (pa0.x & 0xFFFFu);
      uh.u[1] = ((pa0.w & 0xFFFFu) << 16) | (pa0.z & 0xFFFFu);
      uh.u[2] = ((pa1.y & 0xFFFFu) << 16) | (pa1.x & 0xFFFFu);
      uh.u[3] = ((pa1.w & 0xFFFFu) << 16) | (pa1.z & 0xFFFFu);
      ul.u[0] = (pa0.y & 0xFFFF0000u) | (pa0.x >> 16);
      ul.u[1] = (pa0.w & 0xFFFF0000u) | (pa0.z >> 16);
      ul.u[2] = (pa1.y & 0xFFFF0000u) | (pa1.x >> 16);
      ul.u[3] = (pa1.w & 0xFFFF0000u) | (pa1.z >> 16);
      const bfrag ahi = uh.b, alo = ul.b;
      const bfrag bhi0 = *(const bfrag*)&W2T[ch * 128 + (kk ^ swB)];
      const bfrag blo0 = *(const bfrag*)&W2T[ch * 128 + ((64 + kk) ^ swB)];
      const bfrag bhi1 = *(const bfrag*)&W2T[(32 + ch) * 128 + (kk ^ swB)];
      const bfrag blo1 = *(const bfrag*)&W2T[(32 + ch) * 128 + ((64 + kk) ^ swB)];
      if (ks == 0) {
        acc0 = __builtin_amdgcn_mfma_f32_32x32x16_bf16(ahi, bhi0, zero16, 0, 0, 0);
        acc1 = __builtin_amdgcn_mfma_f32_32x32x16_bf16(ahi, bhi1, zero16, 0, 0, 0);
      } else {
        acc0 = __builtin_amdgcn_mfma_f32_32x32x16_bf16(ahi, bhi0, acc0, 0, 0, 0);
        acc1 = __builtin_amdgcn_mfma_f32_32x32x16_bf16(ahi, bhi1, acc1, 0, 0, 0);
      }
      acc0 = __builtin_amdgcn_mfma_f32_32x32x16_bf16(ahi, blo0, acc0, 0, 0, 0);
      acc1 = __builtin_amdgcn_mfma_f32_32x32x16_bf16(ahi, blo1, acc1, 0, 0, 0);
      acc0 = __builtin_amdgcn_mfma_f32_32x32x16_bf16(alo, bhi0, acc0, 0, 0, 0);
      acc1 = __builtin_amdgcn_mfma_f32_32x32x16_bf16(alo, bhi1, acc1, 0, 0, 0);
    }

    // ---- epilogue: rows=points in 16 regs + partner lane (lane^32)
    float s0 = 0, q0 = 0, m0 = -INFINITY, s1 = 0, q1 = 0, m1 = -INFINITY;
#pragma unroll
    for (int i = 0; i < 16; ++i) {
      const float v0 = acc0[i], v1 = acc1[i];
      s0 += v0; q0 = fmaf(v0, v0, q0); m0 = fmaxf(m0, v0 * sg0);
      s1 += v1; q1 = fmaf(v1, v1, q1); m1 = fmaxf(m1, v1 * sg1);
    }
    s0 += __shfl_xor(s0, 32, 64); q0 += __shfl_xor(q0, 32, 64);
    m0 = fmaxf(m0, __shfl_xor(m0, 32, 64));
    s1 += __shfl_xor(s1, 32, 64); q1 += __shfl_xor(q1, 32, 64);
    m1 = fmaxf(m1, __shfl_xor(m1, 32, 64));
    const bool hiHalf = lane >= 32;   // lane's own channel = lane
    psum += hiHalf ? s1 : s0;
    psq += hiHalf ? q1 : q0;
    Y2SEL[(bb * 4 + wv) * 64 + lane] = hiHalf ? m1 : m0;   // coalesced
  }

  // block reduction: alias red arrays onto h1p region (barrier-separated)
  __syncthreads();
  float* redS = (float*)smem;           // 256 floats
  float* redQ = (float*)(smem + 256);   // 256 floats
  redS[wv * 64 + lane] = psum;
  redQ[wv * 64 + lane] = psq;
  __syncthreads();
  if (t < 64) {
    const float s = redS[t] + redS[64 + t] + redS[128 + t] + redS[192 + t];
    const float q = redQ[t] + redQ[64 + t] + redQ[128 + t] + redQ[192 + t];
    P2[t * SB + blockIdx.x] = s;
    P2[(64 + t) * SB + blockIdx.x] = q;
  }
}

// ------------------------------------------------- finalize layer-2 BN params

__global__ void k_fin2(const double* __restrict__ T2, const float* __restrict__ g2,
                       const float* __restrict__ b2, float* __restrict__ params) {
  const int c = threadIdx.x;  // 64
  const double mean = T2[c] / (double)NPTS;
  const double var = T2[64 + c] / (double)NPTS - mean * mean;
  const double a = (double)g2[c] / sqrt(var + 0.001);
  params[128 + c] = (float)a;
  params[192 + c] = (float)((double)b2[c] - mean * a);
}

// ------------------------------------------------- K5: final output pass.

__global__ __launch_bounds__(256) void k_final(
    const float* __restrict__ params, const float* __restrict__ Y2SEL,
    float* __restrict__ out) {
  const int idx = blockIdx.x * 256 + threadIdx.x;   // NPIL*64 total
  const int c = idx & 63;
  const float a2 = params[128 + c];
  const float b2 = params[192 + c];
  const float v = Y2SEL[idx];
  const float sel = (a2 >= 0.0f) ? v : -v;
  out[idx] = fmaxf(fmaf(sel, a2, b2), 0.0f);
}

// ---------------------------------------------------------------- launch

extern "C" void kernel_launch(void* const* d_in, const int* in_sizes, int n_in,
                              void* d_out, int out_size, void* d_ws, size_t ws_size,
                              hipStream_t stream) {
  const float4* vox = (const float4*)d_in[0];
  const int4* coords = (const int4*)d_in[1];
  const int* npnts = (const int*)d_in[2];
  const float* W1 = (const float*)d_in[3];
  const float* g1 = (const float*)d_in[4];
  const float* b1 = (const float*)d_in[5];
  const float* W2 = (const float*)d_in[6];
  const float* g2 = (const float*)d_in[7];
  const float* b2 = (const float*)d_in[8];
  float* out = (float*)d_out;

  char* w = (char*)d_ws;
  size_t off = 0;
  double* T1 = (double*)(w + off); off += 512;                 // 54 doubles
  double* T2 = (double*)(w + off); off += 1024;                // 128 doubles
  float* P1 = (float*)(w + off); off += NMOM * K1_BLOCKS * 4;  // 324 KB
  float* P2 = (float*)(w + off); off += 128 * SB * 4;          // 393 KB
  float* params = (float*)(w + off); off += 256 * 4;           // 256 f32
  float* Y2SEL = (float*)(w + off); off += (size_t)NPIL * 64 * 4;  // 12.3 MB

  k_moments<<<K1_BLOCKS, 256, 0, stream>>>(vox, coords, npnts, P1);
  k_rowreduce<<<NMOM, 256, 0, stream>>>(P1, T1, K1_BLOCKS);
  k_fin1<<<1, 64, 0, stream>>>(T1, W1, g1, b1, params);
  k_stats2<<<SB, 256, 0, stream>>>(vox, coords, npnts, W1, W2, g2, params, P2, Y2SEL);
  k_rowreduce<<<128, 256, 0, stream>>>(P2, T2, SB);
  k_fin2<<<1, 64, 0, stream>>>(T2, g2, b2, params);
  k_final<<<(NPIL * 64) / 256, 256, 0, stream>>>(params, Y2SEL, out);
}

// Round 20
// 99.435 us; speedup vs baseline: 1.2131x; 1.1142x over previous
//
#include <hip/hip_runtime.h>
#include <hip/hip_bf16.h>
#include <math.h>

#define NB 4
#define NPI 12000
#define NM 32
#define NPTS (NB*NPI*NM)      // 1536000
#define NPIL (NB*NPI)         // 48000

// k_moments config
#define K1_BLOCKS 1500
#define K1_STRIDE (K1_BLOCKS*256)   // 384000
#define K1_ITERS 4                  // NPTS / K1_STRIDE
#define NMOM 54                     // 9 Sf + 45 Sff

// heavy-kernel config
#define CHUNK 128
#define NBATCH (NPTS/CHUNK)   // 12000
#define SB 1024               // 4 blocks/CU x 256 CU resident (LDS 32KB)

typedef __attribute__((ext_vector_type(8))) short bfrag;     // 8 bf16 = 4 VGPRs
typedef __attribute__((ext_vector_type(16))) float f32x16;   // MFMA 32x32 acc

// ---------------------------------------------------------------- helpers

__device__ __forceinline__ void make_f(float4 v, int4 cc, int np, int m, float zc, float f[9]) {
  const float cx = ((float)cc.w + 0.5f) * 0.16f + 0.0f;
  const float cy = ((float)cc.z + 0.5f) * 0.16f - 39.68f;
  f[0] = v.x; f[1] = v.y; f[2] = v.z; f[3] = v.w;
  f[4] = v.x - cx; f[5] = v.y - cy; f[6] = cx; f[7] = cy; f[8] = zc;
  const float msk = (m < np) ? 1.0f : 0.0f;
#pragma unroll
  for (int i = 0; i < 9; ++i) f[i] *= msk;
}

// ------------------------------------------------- K1: f-moments

__global__ __launch_bounds__(256) void k_moments(
    const float4* __restrict__ vox, const int4* __restrict__ coords,
    const int* __restrict__ npnts, float* __restrict__ P1) {
  const int t = blockIdx.x * 256 + threadIdx.x;
  float acc[NMOM];
#pragma unroll
  for (int v = 0; v < NMOM; ++v) acc[v] = 0.0f;

#pragma unroll
  for (int j = 0; j < K1_ITERS; ++j) {
    const int pt = t + j * K1_STRIDE;
    const int pil = pt >> 5;
    const int m = pt & 31;
    const float4 v = vox[pt];
    const int4 cc = coords[pil];
    const int np = npnts[pil];
    float z = v.z;
#pragma unroll
    for (int s = 1; s < 32; s <<= 1) z += __shfl_xor(z, s, 32);
    const float zc = z * (1.0f / 32.0f);
    float f[9];
    make_f(v, cc, np, m, zc, f);
    int vi = 0;
#pragma unroll
    for (int i = 0; i < 9; ++i) acc[vi++] += f[i];
#pragma unroll
    for (int i = 0; i < 9; ++i)
#pragma unroll
      for (int jj = i; jj < 9; ++jj) acc[vi++] += f[i] * f[jj];
  }

#pragma unroll
  for (int v = 0; v < NMOM; ++v) {
    float x = acc[v];
#pragma unroll
    for (int s = 1; s < 64; s <<= 1) x += __shfl_xor(x, s, 64);
    acc[v] = x;
  }
  __shared__ float red[4][NMOM];
  const int wave = threadIdx.x >> 6, lane = threadIdx.x & 63;
  if (lane == 0) {
#pragma unroll
    for (int v = 0; v < NMOM; ++v) red[wave][v] = acc[v];
  }
  __syncthreads();
  if (threadIdx.x < NMOM) {
    float s = red[0][threadIdx.x] + red[1][threadIdx.x] + red[2][threadIdx.x] + red[3][threadIdx.x];
    P1[threadIdx.x * K1_BLOCKS + blockIdx.x] = s;
  }
}

// ------------------------------------------------- generic row reduce (f32 -> f64)

__global__ __launch_bounds__(256) void k_rowreduce(
    const float* __restrict__ src, double* __restrict__ dst, int ncols) {
  const int row = blockIdx.x;
  const float* p = src + row * ncols;
  double sd = 0.0;
  for (int i = threadIdx.x; i < ncols; i += 256) sd += (double)p[i];
#pragma unroll
  for (int s = 1; s < 64; s <<= 1) sd += __shfl_xor(sd, s, 64);
  __shared__ double rd[4];
  const int wave = threadIdx.x >> 6, lane = threadIdx.x & 63;
  if (lane == 0) rd[wave] = sd;
  __syncthreads();
  if (threadIdx.x == 0) dst[row] = rd[0] + rd[1] + rd[2] + rd[3];
}

// ------------------------------------------------- finalize layer-1 BN params

__global__ void k_fin1(const double* __restrict__ T1, const float* __restrict__ W1,
                       const float* __restrict__ g1, const float* __restrict__ b1,
                       float* __restrict__ params) {
  const int c = threadIdx.x;  // 64
  double w[9];
#pragma unroll
  for (int i = 0; i < 9; ++i) w[i] = (double)W1[i * 64 + c];
  double mean = 0.0;
#pragma unroll
  for (int i = 0; i < 9; ++i) mean += w[i] * T1[i];
  mean /= (double)NPTS;
  double e2 = 0.0;
  int v = 9;
#pragma unroll
  for (int i = 0; i < 9; ++i)
#pragma unroll
    for (int j = i; j < 9; ++j) {
      const double t = T1[v++] * w[i] * w[j];
      e2 += (i == j) ? t : 2.0 * t;
    }
  e2 /= (double)NPTS;
  const double var = e2 - mean * mean;
  const double a = (double)g1[c] / sqrt(var + 0.001);
  params[c] = (float)a;
  params[64 + c] = (float)((double)b1[c] - mean * a);
}

// ------------------------------------------------- K3: both layers via MFMA, v6
// R19 post-mortem: VALU 64% + MFMA 27% ~= 91% combined issue -- near
// saturation for the mix; must shrink the mix. v6 drops h1's lo-plane:
// h1 stored as ONE RNE bf16 (quantization 2^-9 rel ~ 0.01 abs on y2; W2
// stays split so B-side error ~2^-16). Wins: writeback = relu+cvt+write_b16
// (no residual/packing); A-fragment = direct b128 (no unpack); phase B
// 24 -> 16 MFMAs; h1 LDS 32KB -> 16KB -> total 32768 B -> 4 blocks/CU
// (16 waves/CU), SB 768 -> 1024. Tripwire: absmax jump -> revert to v5.

__global__ __launch_bounds__(256) void k_stats2(
    const float4* __restrict__ vox, const int4* __restrict__ coords,
    const int* __restrict__ npnts, const float* __restrict__ W1,
    const float* __restrict__ W2, const float* __restrict__ g2,
    const float* __restrict__ params, float* __restrict__ P2,
    float* __restrict__ Y2SEL) {
  __shared__ __align__(16) unsigned int smem[8192];   // 32768 B total
  unsigned short* h1 = (unsigned short*)smem;                // [128][64] u16 (swz)
  unsigned short* W2T = (unsigned short*)(smem + 4096);      // [64][128] u16 interleaved (swz)
  // init-only aliases inside the h1 region (dead after reg-hoist + barrier):
  unsigned short* W1Thi = (unsigned short*)smem;             // [64][16]
  unsigned short* W1Tlo = (unsigned short*)(smem + 512);     // [64][16]

  const int t = threadIdx.x;
  // stage W1aug^T split (k padded 10->16): k<9: W1[k][c]*a1[c]; k==9: b1adj[c]
  for (int i = t; i < 1024; i += 256) {
    const int c = i >> 4, k = i & 15;
    float x;
    if (k < 9)       x = W1[k * 64 + c] * params[c];
    else if (k == 9) x = params[64 + c];
    else             x = 0.0f;
    const unsigned int b = __float_as_uint(x);
    W1Thi[c * 16 + k] = (unsigned short)(b >> 16);
    const float r = x - __uint_as_float(b & 0xFFFF0000u);
    W1Tlo[c * 16 + k] = (unsigned short)(__float_as_uint(r) >> 16);
  }
  // stage W2^T split, interleaved+swizzled: hi(ch,k) at col k^sw, lo at (64+k)^sw
  for (int i = t; i < 4096; i += 256) {
    const int k = i >> 6, c = i & 63;
    const float x = W2[i];
    const unsigned int b = __float_as_uint(x);
    const float r = x - __uint_as_float(b & 0xFFFF0000u);
    const int sw = (c & 15) << 3;
    W2T[c * 128 + (k ^ sw)] = (unsigned short)(b >> 16);
    W2T[c * 128 + ((64 + k) ^ sw)] = (unsigned short)(__float_as_uint(r) >> 16);
  }

  const int lane = t & 63;
  const int wv = t >> 6;                      // wave owns pillar wv of each batch
  const int ch = lane & 31;                   // tile-local channel / point id
  const float sg0 = (g2[ch] >= 0.0f) ? 1.0f : -1.0f;
  const float sg1 = (g2[32 + ch] >= 0.0f) ? 1.0f : -1.0f;
  __syncthreads();   // staging visible to all waves

  const int koff = 8 * (lane >> 5);           // k base within 16-wide step
  const int arow = 32 * wv + ch;              // A row (= this lane's point)
  const int swB = (ch & 15) << 3;             // W2T read swizzle (u16 units)
  const int swA = (arow & 7) << 3;            // h1 read swizzle (u16 units)
  // hoist loop-invariant W1aug fragments into registers
  const bfrag w1h0 = *(const bfrag*)&W1Thi[ch * 16 + koff];
  const bfrag w1l0 = *(const bfrag*)&W1Tlo[ch * 16 + koff];
  const bfrag w1h1 = *(const bfrag*)&W1Thi[(32 + ch) * 16 + koff];
  const bfrag w1l1 = *(const bfrag*)&W1Tlo[(32 + ch) * 16 + koff];
  __syncthreads();   // ALL waves done reading W1T staging before h1 overwrite

  // loop-invariant zero accumulator (C operand of each chain's first MFMA)
  f32x16 zero16;
#pragma unroll
  for (int i = 0; i < 16; ++i) zero16[i] = 0.0f;

  float psum = 0.0f, psq = 0.0f;

  // prefetched inputs (this wave's pillar only; halves duplicate points)
  int bb0 = blockIdx.x;
  float4 v = vox[bb0 * CHUNK + 32 * wv + ch];
  int4 cc = coords[bb0 * 4 + wv];
  int np = npnts[bb0 * 4 + wv];

  for (int bb = bb0; bb < NBATCH; bb += SB) {
    // ---- f for this lane's point
    float z = v.z;
#pragma unroll
    for (int s = 1; s < 64; s <<= 1) z += __shfl_xor(z, s, 64);  // 2x duplicated sum
    const float zc = z * (1.0f / 64.0f);
    float f[9];
    make_f(v, cc, np, ch, zc, f);

    // ---- prefetch next iteration's inputs (consumed above)
    {
      const int bbn = bb + SB;
      const int bbs = (bbn < NBATCH) ? bbn : bb;
      v = vox[bbs * CHUNK + 32 * wv + ch];
      cc = coords[bbs * 4 + wv];
      np = npnts[bbs * 4 + wv];
    }

    // ---- build phase-A A-fragments IN-REGISTER (lane-local; no LDS):
    // lanes<32: k=0..7 (f[0..7]); lanes>=32: k=8..15 (f[8], 1.0, 0...)
    bfrag fa_hi, fa_lo;
    {
      unsigned int ahw[4] = {0u, 0u, 0u, 0u}, alw[4] = {0u, 0u, 0u, 0u};
#pragma unroll
      for (int e = 0; e < 8; ++e) {
        const float x = (lane < 32) ? f[e]
                        : ((e == 0) ? f[8] : (e == 1) ? 1.0f : 0.0f);
        const unsigned int b = __float_as_uint(x);
        const float r = x - __uint_as_float(b & 0xFFFF0000u);
        ahw[e >> 1] |= (b >> 16) << ((e & 1) * 16);
        alw[e >> 1] |= (__float_as_uint(r) >> 16) << ((e & 1) * 16);
      }
      union U { unsigned int u[4]; bfrag b; };
      U ch_, cl_;
      ch_.u[0] = ahw[0]; ch_.u[1] = ahw[1]; ch_.u[2] = ahw[2]; ch_.u[3] = ahw[3];
      cl_.u[0] = alw[0]; cl_.u[1] = alw[1]; cl_.u[2] = alw[2]; cl_.u[3] = alw[3];
      fa_hi = ch_.b; fa_lo = cl_.b;
    }

    // ---- phase A: y1aug = f_aug @ W1aug (one k-step, 3 split terms, 2 tiles)
    f32x16 yA0 = __builtin_amdgcn_mfma_f32_32x32x16_bf16(fa_hi, w1h0, zero16, 0, 0, 0);
    f32x16 yA1 = __builtin_amdgcn_mfma_f32_32x32x16_bf16(fa_hi, w1h1, zero16, 0, 0, 0);
    yA0 = __builtin_amdgcn_mfma_f32_32x32x16_bf16(fa_hi, w1l0, yA0, 0, 0, 0);
    yA1 = __builtin_amdgcn_mfma_f32_32x32x16_bf16(fa_hi, w1l1, yA1, 0, 0, 0);
    yA0 = __builtin_amdgcn_mfma_f32_32x32x16_bf16(fa_lo, w1h0, yA0, 0, 0, 0);
    yA1 = __builtin_amdgcn_mfma_f32_32x32x16_bf16(fa_lo, w1h1, yA1, 0, 0, 0);

    // ---- relu + RNE-bf16 + ds_write_b16 (single plane).
    // C layout: row(point) = (reg&3)+8*(reg>>2)+rbase, col = ch (+32 tile1).
    const int rbase = 4 * (lane >> 5);
#pragma unroll
    for (int j = 0; j < 4; ++j) {
      const int swzj = ((j + rbase) & 7) << 3;   // u16 units
      unsigned short* bp0 = &h1[(32 * wv + rbase + j) * 64 + (ch ^ swzj)];
      unsigned short* bp1 = &h1[(32 * wv + rbase + j) * 64 + ((32 + ch) ^ swzj)];
#pragma unroll
      for (int q = 0; q < 4; ++q) {
        const int reg = j + 4 * q;
        {
          const __hip_bfloat16 hb = __float2bfloat16(fmaxf(yA0[reg], 0.0f));
          bp0[q * 512] = *(const unsigned short*)&hb;   // row+8 -> +512 u16
        }
        {
          const __hip_bfloat16 hb = __float2bfloat16(fmaxf(yA1[reg], 0.0f));
          bp1[q * 512] = *(const unsigned short*)&hb;
        }
      }
    }
    // no barrier: wave wrote rows 32wv..32wv+31 and reads only those
    // (within-wave DS ordering)

    // ---- phase B: y2 = h1 @ W2 (4 k-steps, 2 terms, 2 channel tiles)
    f32x16 acc0, acc1;
#pragma unroll
    for (int ks = 0; ks < 4; ++ks) {
      const int kk = koff + 16 * ks;    // multiple of 8
      const bfrag ahi = *(const bfrag*)&h1[arow * 64 + (kk ^ swA)];
      const bfrag bhi0 = *(const bfrag*)&W2T[ch * 128 + (kk ^ swB)];
      const bfrag blo0 = *(const bfrag*)&W2T[ch * 128 + ((64 + kk) ^ swB)];
      const bfrag bhi1 = *(const bfrag*)&W2T[(32 + ch) * 128 + (kk ^ swB)];
      const bfrag blo1 = *(const bfrag*)&W2T[(32 + ch) * 128 + ((64 + kk) ^ swB)];
      if (ks == 0) {
        acc0 = __builtin_amdgcn_mfma_f32_32x32x16_bf16(ahi, bhi0, zero16, 0, 0, 0);
        acc1 = __builtin_amdgcn_mfma_f32_32x32x16_bf16(ahi, bhi1, zero16, 0, 0, 0);
      } else {
        acc0 = __builtin_amdgcn_mfma_f32_32x32x16_bf16(ahi, bhi0, acc0, 0, 0, 0);
        acc1 = __builtin_amdgcn_mfma_f32_32x32x16_bf16(ahi, bhi1, acc1, 0, 0, 0);
      }
      acc0 = __builtin_amdgcn_mfma_f32_32x32x16_bf16(ahi, blo0, acc0, 0, 0, 0);
      acc1 = __builtin_amdgcn_mfma_f32_32x32x16_bf16(ahi, blo1, acc1, 0, 0, 0);
    }

    // ---- epilogue: rows=points in 16 regs + partner lane (lane^32)
    float s0 = 0, q0 = 0, m0 = -INFINITY, s1 = 0, q1 = 0, m1 = -INFINITY;
#pragma unroll
    for (int i = 0; i < 16; ++i) {
      const float v0 = acc0[i], v1 = acc1[i];
      s0 += v0; q0 = fmaf(v0, v0, q0); m0 = fmaxf(m0, v0 * sg0);
      s1 += v1; q1 = fmaf(v1, v1, q1); m1 = fmaxf(m1, v1 * sg1);
    }
    s0 += __shfl_xor(s0, 32, 64); q0 += __shfl_xor(q0, 32, 64);
    m0 = fmaxf(m0, __shfl_xor(m0, 32, 64));
    s1 += __shfl_xor(s1, 32, 64); q1 += __shfl_xor(q1, 32, 64);
    m1 = fmaxf(m1, __shfl_xor(m1, 32, 64));
    const bool hiHalf = lane >= 32;   // lane's own channel = lane
    psum += hiHalf ? s1 : s0;
    psq += hiHalf ? q1 : q0;
    Y2SEL[(bb * 4 + wv) * 64 + lane] = hiHalf ? m1 : m0;   // coalesced
  }

  // block reduction: alias red arrays onto h1 region (barrier-separated)
  __syncthreads();
  float* redS = (float*)smem;           // 256 floats
  float* redQ = (float*)(smem + 256);   // 256 floats
  redS[wv * 64 + lane] = psum;
  redQ[wv * 64 + lane] = psq;
  __syncthreads();
  if (t < 64) {
    const float s = redS[t] + redS[64 + t] + redS[128 + t] + redS[192 + t];
    const float q = redQ[t] + redQ[64 + t] + redQ[128 + t] + redQ[192 + t];
    P2[t * SB + blockIdx.x] = s;
    P2[(64 + t) * SB + blockIdx.x] = q;
  }
}

// ------------------------------------------------- finalize layer-2 BN params

__global__ void k_fin2(const double* __restrict__ T2, const float* __restrict__ g2,
                       const float* __restrict__ b2, float* __restrict__ params) {
  const int c = threadIdx.x;  // 64
  const double mean = T2[c] / (double)NPTS;
  const double var = T2[64 + c] / (double)NPTS - mean * mean;
  const double a = (double)g2[c] / sqrt(var + 0.001);
  params[128 + c] = (float)a;
  params[192 + c] = (float)((double)b2[c] - mean * a);
}

// ------------------------------------------------- K5: final output pass.

__global__ __launch_bounds__(256) void k_final(
    const float* __restrict__ params, const float* __restrict__ Y2SEL,
    float* __restrict__ out) {
  const int idx = blockIdx.x * 256 + threadIdx.x;   // NPIL*64 total
  const int c = idx & 63;
  const float a2 = params[128 + c];
  const float b2 = params[192 + c];
  const float v = Y2SEL[idx];
  const float sel = (a2 >= 0.0f) ? v : -v;
  out[idx] = fmaxf(fmaf(sel, a2, b2), 0.0f);
}

// ---------------------------------------------------------------- launch

extern "C" void kernel_launch(void* const* d_in, const int* in_sizes, int n_in,
                              void* d_out, int out_size, void* d_ws, size_t ws_size,
                              hipStream_t stream) {
  const float4* vox = (const float4*)d_in[0];
  const int4* coords = (const int4*)d_in[1];
  const int* npnts = (const int*)d_in[2];
  const float* W1 = (const float*)d_in[3];
  const float* g1 = (const float*)d_in[4];
  const float* b1 = (const float*)d_in[5];
  const float* W2 = (const float*)d_in[6];
  const float* g2 = (const float*)d_in[7];
  const float* b2 = (const float*)d_in[8];
  float* out = (float*)d_out;

  char* w = (char*)d_ws;
  size_t off = 0;
  double* T1 = (double*)(w + off); off += 512;                 // 54 doubles
  double* T2 = (double*)(w + off); off += 1024;                // 128 doubles
  float* P1 = (float*)(w + off); off += NMOM * K1_BLOCKS * 4;  // 324 KB
  float* P2 = (float*)(w + off); off += 128 * SB * 4;          // 524 KB
  float* params = (float*)(w + off); off += 256 * 4;           // 256 f32
  float* Y2SEL = (float*)(w + off); off += (size_t)NPIL * 64 * 4;  // 12.3 MB

  k_moments<<<K1_BLOCKS, 256, 0, stream>>>(vox, coords, npnts, P1);
  k_rowreduce<<<NMOM, 256, 0, stream>>>(P1, T1, K1_BLOCKS);
  k_fin1<<<1, 64, 0, stream>>>(T1, W1, g1, b1, params);
  k_stats2<<<SB, 256, 0, stream>>>(vox, coords, npnts, W1, W2, g2, params, P2, Y2SEL);
  k_rowreduce<<<128, 256, 0, stream>>>(P2, T2, SB);
  k_fin2<<<1, 64, 0, stream>>>(T2, g2, b2, params);
  k_final<<<(NPIL * 64) / 256, 256, 0, stream>>>(params, Y2SEL, out);
}